// Round 9
// baseline (327.107 us; speedup 1.0000x reference)
//
#include <hip/hip_runtime.h>
#include <hip/hip_bf16.h>

typedef __bf16 bf16x8_t __attribute__((ext_vector_type(8)));
typedef float f32x4_t __attribute__((ext_vector_type(4)));
typedef float f32x2_t __attribute__((ext_vector_type(2)));

__device__ __forceinline__ float bits2f(unsigned int u) {
    union { unsigned int u; float f; } c; c.u = u; return c.f;
}
__device__ __forceinline__ unsigned short f2bf_bits(float f) {
    __hip_bfloat16 h = __float2bfloat16(f);
    return __builtin_bit_cast(unsigned short, h);
}
__device__ __forceinline__ f32x2_t unpack_bf2(unsigned int u) {
    return (f32x2_t){bits2f(u << 16), bits2f(u & 0xffff0000u)};
}
// XCD id (0..7) — HW_REG_XCC_ID, wave-uniform; workgroup lives on one CU/XCD.
__device__ __forceinline__ int get_xcd() {
    unsigned v;
    asm volatile("s_getreg_b32 %0, hwreg(HW_REG_XCC_ID)" : "=s"(v));
    return (int)(v & 7);
}

// ---------------- sentinel (ws too small) ----------------
__global__ void sentinel_fill(float* __restrict__ out, int n) {
    int i = blockIdx.x * blockDim.x + threadIdx.x;
    if (i < n) out[i] = 100.0f;
}

// ---------------- init: edge dtype detect (block 0) + cnt8 zeroing (blocks 1..) ----------------
__global__ void init_combo(const unsigned int* __restrict__ ei, int* __restrict__ flags,
                           unsigned* __restrict__ cnt8, int Mln) {
    if (blockIdx.x == 0) {
        if (threadIdx.x < 64) {
            int lane = threadIdx.x;
            int cz = 0;
            #pragma unroll
            for (int j = 0; j < 4; ++j) {
                int idx = lane * 4 + j;          // 0..255
                cz += (ei[2 * idx + 1] == 0u);   // odd words zero => int64 storage
            }
            #pragma unroll
            for (int off = 32; off; off >>= 1) cz += __shfl_down(cz, off);
            if (lane == 0) flags[0] = (cz > 200);
        }
    } else {
        int i = (blockIdx.x - 1) * 256 + threadIdx.x;
        if (i < Mln) cnt8[i] = 0u;
    }
}

// ---------------- CSR build ----------------
// XCD-sliced counters: cnt8[xcd][c]. Each address touched by exactly ONE XCD, so
// workgroup-scope atomics execute in the local XCD L2 (fast path) instead of the
// memory-side coherent path. (R7/R8: agent-scope atomics hit a fixed ~19G ops/s
// wall, layout/ILP-independent: 41-42 µs @ VALUBusy <1%.) rank = local rank within
// (xcd,c); global slot = colptr[c] + base8[xcd][c] + rank.
__global__ void count_rank_xcd(const int* __restrict__ ei, unsigned* __restrict__ cnt8,
                               int* __restrict__ rank, int* __restrict__ c32,
                               int* __restrict__ r32, unsigned char* __restrict__ xcd8,
                               int E, int M, const int* __restrict__ flags) {
    int e = blockIdx.x * 256 + threadIdx.x;
    int xcd = get_xcd();
    if (e < E) {
        int r, c;
        if (flags[0]) { r = ei[2 * e]; c = ei[2 * E + 2 * e]; }
        else          { r = ei[e];     c = ei[E + e]; }
        c32[e] = c;
        r32[e] = r;
        xcd8[e] = (unsigned char)xcd;
        int rk = 0;
        if ((unsigned)c < (unsigned)M)
            rk = (int)__hip_atomic_fetch_add(&cnt8[(size_t)xcd * M + c], 1u,
                                             __ATOMIC_RELAXED, __HIP_MEMORY_SCOPE_WORKGROUP);
        rank[e] = rk;
    }
}

// per-256-block exclusive scan of totals; also emits per-XCD base offsets + totals
__global__ void scan_blocks_x(const unsigned* __restrict__ cnt8, unsigned* __restrict__ base8,
                              int* __restrict__ tot, int* __restrict__ excl,
                              int* __restrict__ bsum, int M) {
    int tid = threadIdx.x;
    int i = blockIdx.x * 256 + tid;
    int lane = tid & 63, wv = tid >> 6;
    __shared__ int ws[4];
    int v = 0;
    if (i < M) {
        unsigned run = 0;
        #pragma unroll
        for (int x = 0; x < 8; ++x) {
            unsigned cv = cnt8[(size_t)x * M + i];
            base8[(size_t)x * M + i] = run;
            run += cv;
        }
        v = (int)run;
        tot[i] = v;
    }
    int s = v;
    #pragma unroll
    for (int off = 1; off < 64; off <<= 1) {
        int t = __shfl_up(s, off);
        if (lane >= off) s += t;
    }
    if (lane == 63) ws[wv] = s;
    __syncthreads();
    if (tid == 0) { int a = 0; for (int q = 0; q < 4; ++q) { int t = ws[q]; ws[q] = a; a += t; } }
    __syncthreads();
    int ex = s - v + ws[wv];
    if (i < M) excl[i] = ex;
    if (tid == 255) bsum[blockIdx.x] = ex + v;
}

__global__ void scan_bsums(const int* __restrict__ bsum, int* __restrict__ boff,
                           int nb, int* __restrict__ colptr, int n) {
    int tid = threadIdx.x, lane = tid & 63, wv = tid >> 6;
    __shared__ int ws[4];
    __shared__ int carry;
    if (tid == 0) carry = 0;
    __syncthreads();
    for (int base = 0; base < nb; base += 256) {
        int i = base + tid;
        int v = (i < nb) ? bsum[i] : 0;
        int s = v;
        #pragma unroll
        for (int off = 1; off < 64; off <<= 1) {
            int t = __shfl_up(s, off);
            if (lane >= off) s += t;
        }
        if (lane == 63) ws[wv] = s;
        __syncthreads();
        if (tid == 0) { int a = carry; for (int q = 0; q < 4; ++q) { int t = ws[q]; ws[q] = a; a += t; } carry = a; }
        __syncthreads();
        int ex = s - v + ws[wv];
        if (i < nb) boff[i] = ex;
        __syncthreads();
    }
    if (tid == 0) colptr[n] = carry;
}

__global__ void scan_add_dinv(const int* __restrict__ excl, const int* __restrict__ boff,
                              const int* __restrict__ tot, int* __restrict__ colptr,
                              float* __restrict__ dinv, int n) {
    int i = blockIdx.x * 256 + threadIdx.x;
    if (i < n) {
        colptr[i] = excl[i] + boff[blockIdx.x];
        dinv[i] = rsqrtf((float)tot[i] + 1.0f);
    }
}

__global__ void fill_csr_part2(const int* __restrict__ c32, const int* __restrict__ r32,
                               const unsigned char* __restrict__ xcd8,
                               const unsigned* __restrict__ base8,
                               const int* __restrict__ colptr, const int* __restrict__ rank,
                               int* __restrict__ esrc, int E, int M, int psz) {
    int part = blockIdx.x & 7;
    int e = (blockIdx.x >> 3) * 256 + threadIdx.x;
    int lo = part * psz;
    int hi = lo + psz; if (hi > M) hi = M;
    if (e < E) {
        int c = c32[e];
        if (c >= lo && c < hi) {
            int r = r32[e];
            if ((unsigned)r < (unsigned)M) {
                int p = colptr[c] + (int)base8[(size_t)xcd8[e] * M + c] + rank[e];
                if ((unsigned)p < (unsigned)E) esrc[p] = r;
            }
        }
    }
}

// ---------------- fused prep: x pre-scale -> fp8 table + weight transposes ----------------
__global__ void prep_fused(const float* __restrict__ x, const float* __restrict__ dinv,
                           unsigned char* __restrict__ xs8,
                           const float* __restrict__ W1, const float* __restrict__ W2,
                           const float* __restrict__ W3,
                           unsigned short* __restrict__ Wt1, unsigned short* __restrict__ Wt2,
                           unsigned short* __restrict__ Wt3,
                           int M, int nps) {
    if ((int)blockIdx.x < nps) {
        int i = blockIdx.x * 256 + threadIdx.x;      // group of 4 channels
        if (i < M * 32) {
            int row = i >> 5;                        // 32 groups per 128-ch row
            float dv = dinv[row];
            float4 v = *(const float4*)(x + (size_t)i * 4);
            unsigned u = __builtin_amdgcn_cvt_pk_fp8_f32(v.x * dv, v.y * dv, 0, false);
            u = __builtin_amdgcn_cvt_pk_fp8_f32(v.z * dv, v.w * dv, u, true);
            *(unsigned*)(xs8 + (size_t)i * 4) = u;
        }
    } else {
        int i = ((int)blockIdx.x - nps) * 256 + threadIdx.x;
        if (i < 32768) {                       // W1: 128x256
            int k = i >> 8, n = i & 255;
            Wt1[n * 128 + k] = f2bf_bits(W1[i]);
        } else if (i < 32768 + 65536) {        // W2: 256x256
            int j = i - 32768;
            int k = j >> 8, n = j & 255;
            Wt2[n * 256 + k] = f2bf_bits(W2[j]);
        } else if (i < 114688) {               // W3: 256x64
            int j = i - 98304;
            int k = j >> 6, n = j & 63;
            Wt3[n * 256 + k] = f2bf_bits(W3[j]);
        }
    }
}

// ---------------- tiled GEMM (bf16 MFMA), K-split staging ----------------
// EPI=0: Y(bf16) = dinv[m] * (A·B)
// EPI=1: Y(bf16) = sigmoid(A·B + bias[n])
// EPI=2: Y(fp8 e4m3) = dinv[m] * (A·B)    (row-major store)
template<int K, int BN, int NTOT, int EPI>
__global__ __launch_bounds__(256) void gemm_tile(
    const __bf16* __restrict__ A,
    const unsigned short* __restrict__ Bt,
    const float* __restrict__ dinv,
    const float* __restrict__ bias,
    void* __restrict__ Y,
    int M)
{
    constexpr int KS = (K > 128) ? 128 : K;   // staged chunk
    constexpr int KP = KS + 8;
    constexpr int NT = BN / 2 / 16;   // n-tiles per wave
    __shared__ unsigned short Bs[BN * KP];

    const int tid  = threadIdx.x;
    const int lane = tid & 63;
    const int wave = tid >> 6;        // 0..3
    const int wm   = wave >> 1;       // 0..1  row group
    const int wn   = wave & 1;        // 0..1  col group
    const int quad = lane >> 4;       // 0..3
    const int l16  = lane & 15;
    const int n0   = blockIdx.y * BN;

    int mrow[4];
#pragma unroll
    for (int mt = 0; mt < 4; ++mt) {
        int r = blockIdx.x * 128 + wm * 64 + mt * 16 + l16;
        mrow[mt] = (r < M) ? r : (M - 1);
    }

    f32x4_t acc[4][NT];
#pragma unroll
    for (int mt = 0; mt < 4; ++mt)
#pragma unroll
        for (int t = 0; t < NT; ++t) acc[mt][t] = (f32x4_t){0.f, 0.f, 0.f, 0.f};

    const unsigned short* BsW = &Bs[(wn * (BN / 2)) * KP];

    for (int kh = 0; kh < K; kh += KS) {
        constexpr int CH = BN * KS / 8;    // 16B chunks
        for (int idx = tid; idx < CH; idx += 256) {
            int n  = idx / (KS / 8);
            int k8 = idx - n * (KS / 8);
            uint4 v = *(const uint4*)(Bt + (size_t)(n0 + n) * K + kh + k8 * 8);
            *(uint4*)&Bs[n * KP + k8 * 8] = v;
        }
        __syncthreads();

#pragma unroll
        for (int kc = 0; kc < KS; kc += 32) {
            bf16x8_t a[4], b[NT];
#pragma unroll
            for (int mt = 0; mt < 4; ++mt)
                a[mt] = *(const bf16x8_t*)(A + (size_t)mrow[mt] * K + kh + kc + quad * 8);
#pragma unroll
            for (int t = 0; t < NT; ++t)
                b[t] = *(const bf16x8_t*)&BsW[(t * 16 + l16) * KP + kc + quad * 8];
#pragma unroll
            for (int mt = 0; mt < 4; ++mt)
#pragma unroll
                for (int t = 0; t < NT; ++t)
                    acc[mt][t] = __builtin_amdgcn_mfma_f32_16x16x32_bf16(a[mt], b[t], acc[mt][t], 0, 0, 0);
        }
        if (kh + KS < K) __syncthreads();
    }

    float bv[NT];
    if constexpr (EPI == 1) {
#pragma unroll
        for (int t = 0; t < NT; ++t)
            bv[t] = bias[n0 + wn * (BN / 2) + t * 16 + l16];
    }

#pragma unroll
    for (int mt = 0; mt < 4; ++mt) {
        int rowbase = blockIdx.x * 128 + wm * 64 + mt * 16 + quad * 4;
#pragma unroll
        for (int r = 0; r < 4; ++r) {
            int rrow = rowbase + r;
            if (rrow < M) {
                if constexpr (EPI == 0) {
                    float dv = dinv[rrow];
#pragma unroll
                    for (int t = 0; t < NT; ++t) {
                        int ccol = n0 + wn * (BN / 2) + t * 16 + l16;
                        ((__hip_bfloat16*)Y)[(size_t)rrow * NTOT + ccol] =
                            __float2bfloat16(acc[mt][t][r] * dv);
                    }
                } else if constexpr (EPI == 1) {
#pragma unroll
                    for (int t = 0; t < NT; ++t) {
                        int ccol = n0 + wn * (BN / 2) + t * 16 + l16;
                        float o = acc[mt][t][r] + bv[t];
                        o = 1.f / (1.f + __expf(-o));
                        ((__hip_bfloat16*)Y)[(size_t)rrow * NTOT + ccol] = __float2bfloat16(o);
                    }
                } else {
                    float dv = dinv[rrow];
#pragma unroll
                    for (int t = 0; t < NT; ++t) {
                        int ccol = n0 + wn * (BN / 2) + t * 16 + l16;
                        float o = acc[mt][t][r] * dv;
                        int pk = __builtin_amdgcn_cvt_pk_fp8_f32(o, o, 0, false);
                        ((unsigned char*)Y)[(size_t)rrow * NTOT + ccol] = (unsigned char)(pk & 0xff);
                    }
                }
            }
        }
    }
}

// ================= aggregations =================
// fp8 C=256 (layer 2): wave covers one 256B row, 4B/lane. 2-deep x 8-wide pipeline.
// (Best measured: 42.4 µs @ 83 MB compulsory fetch. Chunk-split variants (R5/R6)
//  cut fetch to 61 MB but cost 57-61 µs — L2 miss-concurrency wall makes the
//  second edge-list walk costlier than the saved traffic. Do not re-split.)
__global__ __launch_bounds__(256) void aggregate_fp8_v4(
    const unsigned char* __restrict__ Y8,
    const int* __restrict__ colptr,
    const int* __restrict__ esrc,
    const float* __restrict__ dinv,
    const float* __restrict__ bias,
    unsigned short* __restrict__ H,
    int M, int Etot)
{
    const int lane = threadIdx.x & 63;
    const int wave = threadIdx.x >> 6;
    int node = blockIdx.x * 4 + wave;
    if (node >= M) return;

    int s = colptr[node];
    int e = colptr[node + 1];
    if (s < 0) s = 0;
    if (e > Etot) e = Etot;
    if (e < s) e = s;
    int n = e - s;

    const char* Yb = (const char*)Y8;
    const unsigned lb = (unsigned)(lane * 4);

    unsigned su = *(const unsigned*)(Yb + (((unsigned)node) << 8) + lb);

    f32x2_t a0 = {0.f, 0.f}, a1 = {0.f, 0.f};

    auto gather8 = [&](unsigned* u, int base) {
        #pragma unroll
        for (int k = 0; k < 8; ++k) {
            unsigned off = (((unsigned)esrc[s + base + k]) << 8) + lb;
            u[k] = *(const unsigned*)(Yb + off);
        }
    };
    auto acc8 = [&](const unsigned* u) {
        #pragma unroll
        for (int k = 0; k < 8; ++k) {
            a0 += __builtin_amdgcn_cvt_pk_f32_fp8(u[k], false);
            a1 += __builtin_amdgcn_cvt_pk_f32_fp8(u[k], true);
        }
    };

    unsigned ua[8], ub[8];
    int NB = n >> 3;
    if (NB > 0) {
        gather8(ua, 0);
        int i = 1;
        for (; i + 1 < NB; i += 2) {
            gather8(ub, i << 3);
            acc8(ua);
            gather8(ua, (i + 1) << 3);
            acc8(ub);
        }
        if (i < NB) {
            gather8(ub, i << 3);
            acc8(ua);
            acc8(ub);
        } else {
            acc8(ua);
        }
    }
    #pragma unroll 2
    for (int t = NB << 3; t < n; ++t) {
        unsigned off = (((unsigned)esrc[s + t]) << 8) + lb;
        unsigned u = *(const unsigned*)(Yb + off);
        a0 += __builtin_amdgcn_cvt_pk_f32_fp8(u, false);
        a1 += __builtin_amdgcn_cvt_pk_f32_fp8(u, true);
    }
    a0 += __builtin_amdgcn_cvt_pk_f32_fp8(su, false);
    a1 += __builtin_amdgcn_cvt_pk_f32_fp8(su, true);

    float dv = dinv[node];
    float4 bv = *(const float4*)(bias + lane * 4);
    float o0 = a0[0] * dv + bv.x;
    float o1 = a0[1] * dv + bv.y;
    float o2 = a1[0] * dv + bv.z;
    float o3 = a1[1] * dv + bv.w;
    o0 = 1.f / (1.f + __expf(-o0));
    o1 = 1.f / (1.f + __expf(-o1));
    o2 = 1.f / (1.f + __expf(-o2));
    o3 = 1.f / (1.f + __expf(-o3));
    uint2 st;
    st.x = (unsigned)f2bf_bits(o0) | ((unsigned)f2bf_bits(o1) << 16);
    st.y = (unsigned)f2bf_bits(o2) | ((unsigned)f2bf_bits(o3) << 16);
    *(uint2*)(H + (size_t)node * 256 + lane * 4) = st;
}

// fp8 C=128 (layer-1 xs aggregation): 128B rows, uint2/16-lane, batch-8 ping-pong.
__global__ __launch_bounds__(256) void aggregate_xs8b(
    const unsigned char* __restrict__ X8,
    const int* __restrict__ colptr,
    const int* __restrict__ esrc,
    const float* __restrict__ dinv,
    unsigned short* __restrict__ xa,
    int M, int Etot)
{
    const int lane = threadIdx.x & 63;
    const int wave = threadIdx.x >> 6;
    const int l4 = lane & 15;
    const int g4 = lane >> 4;
    int node = blockIdx.x * 4 + wave;
    if (node >= M) return;

    int s = colptr[node];
    int e = colptr[node + 1];
    if (s < 0) s = 0;
    if (e > Etot) e = Etot;
    if (e < s) e = s;
    int n = e - s;

    const char* Yb = (const char*)X8;
    const unsigned lb = (unsigned)(l4 * 8);

    uint2 su = {0u, 0u};
    if (g4 == 0) su = *(const uint2*)(Yb + ((unsigned)node) * 128u + lb);

    f32x2_t a0 = {0.f, 0.f}, a1 = {0.f, 0.f}, a2 = {0.f, 0.f}, a3 = {0.f, 0.f};

    auto gat = [&](uint2* u, int base) {
        u[0] = *(const uint2*)(Yb + ((unsigned)esrc[s + base + g4]) * 128u + lb);
        u[1] = *(const uint2*)(Yb + ((unsigned)esrc[s + base + 4 + g4]) * 128u + lb);
    };
    auto acc = [&](const uint2* u) {
        #pragma unroll
        for (int k = 0; k < 2; ++k) {
            a0 += __builtin_amdgcn_cvt_pk_f32_fp8(u[k].x, false);
            a1 += __builtin_amdgcn_cvt_pk_f32_fp8(u[k].x, true);
            a2 += __builtin_amdgcn_cvt_pk_f32_fp8(u[k].y, false);
            a3 += __builtin_amdgcn_cvt_pk_f32_fp8(u[k].y, true);
        }
    };

    uint2 ua[2], ub[2];
    int NB = n >> 3;
    if (NB > 0) {
        gat(ua, 0);
        int i = 1;
        for (; i + 1 < NB; i += 2) {
            gat(ub, i << 3); acc(ua);
            gat(ua, (i + 1) << 3); acc(ub);
        }
        if (i < NB) { gat(ub, i << 3); acc(ua); acc(ub); }
        else acc(ua);
    }
    for (int t = NB << 3; t < n; t += 4) {
        if (t + g4 < n) {
            uint2 u = *(const uint2*)(Yb + ((unsigned)esrc[s + t + g4]) * 128u + lb);
            a0 += __builtin_amdgcn_cvt_pk_f32_fp8(u.x, false);
            a1 += __builtin_amdgcn_cvt_pk_f32_fp8(u.x, true);
            a2 += __builtin_amdgcn_cvt_pk_f32_fp8(u.y, false);
            a3 += __builtin_amdgcn_cvt_pk_f32_fp8(u.y, true);
        }
    }
    if (g4 == 0) {
        a0 += __builtin_amdgcn_cvt_pk_f32_fp8(su.x, false);
        a1 += __builtin_amdgcn_cvt_pk_f32_fp8(su.x, true);
        a2 += __builtin_amdgcn_cvt_pk_f32_fp8(su.y, false);
        a3 += __builtin_amdgcn_cvt_pk_f32_fp8(su.y, true);
    }

    #pragma unroll
    for (int off = 16; off < 64; off <<= 1) {
        a0[0] += __shfl_xor(a0[0], off); a0[1] += __shfl_xor(a0[1], off);
        a1[0] += __shfl_xor(a1[0], off); a1[1] += __shfl_xor(a1[1], off);
        a2[0] += __shfl_xor(a2[0], off); a2[1] += __shfl_xor(a2[1], off);
        a3[0] += __shfl_xor(a3[0], off); a3[1] += __shfl_xor(a3[1], off);
    }

    if (g4 == 0) {   // channels [l4*8, +8)
        float dv = dinv[node];
        uint4 st;
        st.x = (unsigned)f2bf_bits(a0[0] * dv) | ((unsigned)f2bf_bits(a0[1] * dv) << 16);
        st.y = (unsigned)f2bf_bits(a1[0] * dv) | ((unsigned)f2bf_bits(a1[1] * dv) << 16);
        st.z = (unsigned)f2bf_bits(a2[0] * dv) | ((unsigned)f2bf_bits(a2[1] * dv) << 16);
        st.w = (unsigned)f2bf_bits(a3[0] * dv) | ((unsigned)f2bf_bits(a3[1] * dv) << 16);
        *(uint4*)(xa + (size_t)node * 128 + l4 * 8) = st;
    }
}

// bf16 C=64, f32 out + bias (layer 3): 128B rows, uint2/16-lane, batch-8 ping-pong.
__global__ __launch_bounds__(256) void aggregate_bf16_64_v5(
    const unsigned short* __restrict__ Yin,
    const int* __restrict__ colptr,
    const int* __restrict__ esrc,
    const float* __restrict__ dinv,
    const float* __restrict__ bias,
    float* __restrict__ out,
    int M, int Etot)
{
    const int lane = threadIdx.x & 63;
    const int wave = threadIdx.x >> 6;
    const int l4 = lane & 15;
    const int g4 = lane >> 4;
    int node = blockIdx.x * 4 + wave;
    if (node >= M) return;

    int s = colptr[node];
    int e = colptr[node + 1];
    if (s < 0) s = 0;
    if (e > Etot) e = Etot;
    if (e < s) e = s;
    int n = e - s;

    const char* Yb = (const char*)Yin;
    const unsigned lb = (unsigned)(l4 * 8);

    uint2 su = {0u, 0u};
    if (g4 == 0) su = *(const uint2*)(Yb + ((unsigned)node) * 128u + lb);

    f32x2_t a0 = {0.f, 0.f}, a1 = {0.f, 0.f};

    auto gat = [&](uint2* u, int base) {
        u[0] = *(const uint2*)(Yb + ((unsigned)esrc[s + base + g4]) * 128u + lb);
        u[1] = *(const uint2*)(Yb + ((unsigned)esrc[s + base + 4 + g4]) * 128u + lb);
    };
    auto acc = [&](const uint2* u) {
        #pragma unroll
        for (int k = 0; k < 2; ++k) {
            a0 += unpack_bf2(u[k].x);
            a1 += unpack_bf2(u[k].y);
        }
    };

    uint2 ua[2], ub[2];
    int NB = n >> 3;
    if (NB > 0) {
        gat(ua, 0);
        int i = 1;
        for (; i + 1 < NB; i += 2) {
            gat(ub, i << 3); acc(ua);
            gat(ua, (i + 1) << 3); acc(ub);
        }
        if (i < NB) { gat(ub, i << 3); acc(ua); acc(ub); }
        else acc(ua);
    }
    for (int t = NB << 3; t < n; t += 4) {
        if (t + g4 < n) {
            uint2 u = *(const uint2*)(Yb + ((unsigned)esrc[s + t + g4]) * 128u + lb);
            a0 += unpack_bf2(u.x);
            a1 += unpack_bf2(u.y);
        }
    }
    if (g4 == 0) {
        a0 += unpack_bf2(su.x);
        a1 += unpack_bf2(su.y);
    }

    #pragma unroll
    for (int off = 16; off < 64; off <<= 1) {
        a0[0] += __shfl_xor(a0[0], off); a0[1] += __shfl_xor(a0[1], off);
        a1[0] += __shfl_xor(a1[0], off); a1[1] += __shfl_xor(a1[1], off);
    }

    if (g4 == 0) {   // channels [l4*4, +4)
        float dv = dinv[node];
        float4 bv = *(const float4*)(bias + l4 * 4);
        float4 st;
        st.x = a0[0] * dv + bv.x;
        st.y = a0[1] * dv + bv.y;
        st.z = a1[0] * dv + bv.z;
        st.w = a1[1] * dv + bv.w;
        *(float4*)(out + (size_t)node * 64 + l4 * 4) = st;
    }
}

// ---------------- launch ----------------

extern "C" void kernel_launch(void* const* d_in, const int* in_sizes, int n_in,
                              void* d_out, int out_size, void* d_ws, size_t ws_size,
                              hipStream_t stream)
{
    int iEI = 2, iW1 = 3, iB1 = 4, iW2 = 5, iB2 = 6, iW3 = 7, iB3 = 8;
    if (n_in == 8) { iEI = 1; iW1 = 2; iB1 = 3; iW2 = 4; iB2 = 5; iW3 = 6; iB3 = 7; }

    const float* x  = (const float*)d_in[0];
    const int* ei   = (const int*)d_in[iEI];
    const float* W1 = (const float*)d_in[iW1];
    const float* b1 = (const float*)d_in[iB1];
    const float* W2 = (const float*)d_in[iW2];
    const float* b2 = (const float*)d_in[iB2];
    const float* W3 = (const float*)d_in[iW3];
    const float* b3 = (const float*)d_in[iB3];

    const int M = in_sizes[0] / 128;     // 50000
    const int E = in_sizes[iEI] / 2;     // 800000
    const int NB = (M + 255) / 256;      // scan blocks
    const int PSZ = (M + 7) / 8;         // nodes per fill partition

    auto rnd = [](size_t b) { return (b + 255) & ~(size_t)255; };
    size_t needed = rnd(64 * 4)                          // flags
                  + rnd((size_t)M * 4)                   // dinv
                  + rnd((size_t)M * 32) * 2              // cnt8, base8 (8 XCD slices)
                  + rnd((size_t)M * 4)                   // tot
                  + rnd((size_t)(M + 1) * 4)             // colptr
                  + rnd((size_t)M * 4)                   // excl
                  + rnd((size_t)(NB + 1) * 4) * 2        // bsum, boff
                  + rnd((size_t)E * 4) * 4               // esrc, rank, c32, r32
                  + rnd((size_t)E)                       // xcd8
                  + rnd((size_t)256 * 128 * 2)           // Wt1
                  + rnd((size_t)256 * 256 * 2)           // Wt2
                  + rnd((size_t)64 * 256 * 2)            // Wt3
                  + rnd((size_t)M * 256 * 2) * 2;        // ybuf, hbuf
    if (ws_size < needed) {
        sentinel_fill<<<(out_size + 255) / 256, 256, 0, stream>>>((float*)d_out, out_size);
        return;
    }

    char* p = (char*)d_ws;
    auto alloc = [&](size_t bytes) {
        char* r = p;
        p += (bytes + 255) & ~(size_t)255;
        return r;
    };
    int* flags  = (int*)alloc(64 * 4);
    float* dinv = (float*)alloc((size_t)M * 4);
    unsigned* cnt8  = (unsigned*)alloc((size_t)M * 32);
    unsigned* base8 = (unsigned*)alloc((size_t)M * 32);
    int* tot    = (int*)alloc((size_t)M * 4);
    int* colptr = (int*)alloc((size_t)(M + 1) * 4);
    int* excl   = (int*)alloc((size_t)M * 4);
    int* bsum   = (int*)alloc((size_t)(NB + 1) * 4);
    int* boff   = (int*)alloc((size_t)(NB + 1) * 4);
    int* esrc   = (int*)alloc((size_t)E * 4);
    int* rank   = (int*)alloc((size_t)E * 4);
    int* c32    = (int*)alloc((size_t)E * 4);
    int* r32    = (int*)alloc((size_t)E * 4);
    unsigned char* xcd8 = (unsigned char*)alloc((size_t)E);
    unsigned short* Wt1 = (unsigned short*)alloc((size_t)256 * 128 * 2);
    unsigned short* Wt2 = (unsigned short*)alloc((size_t)256 * 256 * 2);
    unsigned short* Wt3 = (unsigned short*)alloc((size_t)64 * 256 * 2);
    __hip_bfloat16* ybuf = (__hip_bfloat16*)alloc((size_t)M * 256 * 2);
    __hip_bfloat16* hbuf = (__hip_bfloat16*)alloc((size_t)M * 256 * 2);

    // region reuse inside ybuf:
    unsigned char* xs8 = (unsigned char*)ybuf;                     // M x 128 fp8 (6.4MB)
    unsigned short* xa = (unsigned short*)ybuf + (size_t)M * 128;  // M x 128 bf16 (at +12.8MB)
    unsigned char*  y8 = (unsigned char*)ybuf;                     // M x 256 fp8 row-major (after xs8 dead)

    // init: detect dtype (block 0) + zero cnt8 (blocks 1..)
    int Mln = M * 8;
    init_combo<<<(Mln + 255) / 256 + 1, 256, 0, stream>>>(
        (const unsigned int*)ei, flags, cnt8, Mln);

    count_rank_xcd<<<(E + 255) / 256, 256, 0, stream>>>(
        ei, cnt8, rank, c32, r32, xcd8, E, M, flags);
    scan_blocks_x<<<NB, 256, 0, stream>>>(cnt8, base8, tot, excl, bsum, M);
    scan_bsums<<<1, 256, 0, stream>>>(bsum, boff, NB, colptr, M);
    scan_add_dinv<<<NB, 256, 0, stream>>>(excl, boff, tot, colptr, dinv, M);
    fill_csr_part2<<<((E + 255) / 256) * 8, 256, 0, stream>>>(
        c32, r32, xcd8, base8, colptr, rank, esrc, E, M, PSZ);

    int gmb = (M + 127) / 128;           // 391
    int ga  = (M + 3) / 4;               // 12500
    int nps = (M * 32 + 255) / 256;      // prescale blocks (4 ch/thread)

    // fused prep: fp8 prescale of x + weight transposes (needs dinv)
    prep_fused<<<nps + 448, 256, 0, stream>>>(
        x, dinv, xs8, W1, W2, W3, Wt1, Wt2, Wt3, M, nps);

    // Layer 1: aggregate fp8 xs (S·x), then GEMM with fused bias+sigmoid
    aggregate_xs8b<<<ga, 256, 0, stream>>>(
        xs8, colptr, esrc, dinv, xa, M, E);
    gemm_tile<128, 128, 256, 1><<<dim3(gmb, 2), 256, 0, stream>>>(
        (const __bf16*)xa, Wt1, dinv, b1, hbuf, M);
    // Layer 2: GEMM -> fp8 table (row-major), fp8 gather aggregate -> bf16 h2
    gemm_tile<256, 128, 256, 2><<<dim3(gmb, 2), 256, 0, stream>>>(
        (const __bf16*)hbuf, Wt2, dinv, b2, y8, M);
    aggregate_fp8_v4<<<ga, 256, 0, stream>>>(
        y8, colptr, esrc, dinv, b2, (unsigned short*)hbuf, M, E);
    // Layer 3: bf16
    gemm_tile<256, 64, 64, 0><<<dim3(gmb, 1), 256, 0, stream>>>(
        (const __bf16*)hbuf, Wt3, dinv, b3, ybuf, M);
    aggregate_bf16_64_v5<<<ga, 256, 0, stream>>>(
        (const unsigned short*)ybuf, colptr, esrc, dinv, b3, (float*)d_out, M, E);
}

// Round 10
// 315.683 us; speedup vs baseline: 1.0362x; 1.0362x over previous
//
#include <hip/hip_runtime.h>
#include <hip/hip_bf16.h>

typedef __bf16 bf16x8_t __attribute__((ext_vector_type(8)));
typedef float f32x4_t __attribute__((ext_vector_type(4)));
typedef float f32x2_t __attribute__((ext_vector_type(2)));

__device__ __forceinline__ float bits2f(unsigned int u) {
    union { unsigned int u; float f; } c; c.u = u; return c.f;
}
__device__ __forceinline__ unsigned short f2bf_bits(float f) {
    __hip_bfloat16 h = __float2bfloat16(f);
    return __builtin_bit_cast(unsigned short, h);
}
__device__ __forceinline__ f32x2_t unpack_bf2(unsigned int u) {
    return (f32x2_t){bits2f(u << 16), bits2f(u & 0xffff0000u)};
}
// XCD id (0..7) — HW_REG_XCC_ID, wave-uniform; workgroup lives on one CU/XCD.
__device__ __forceinline__ int get_xcd() {
    unsigned v;
    asm volatile("s_getreg_b32 %0, hwreg(HW_REG_XCC_ID)" : "=s"(v));
    return (int)(v & 7);
}

// ---------------- sentinel (ws too small) ----------------
__global__ void sentinel_fill(float* __restrict__ out, int n) {
    int i = blockIdx.x * blockDim.x + threadIdx.x;
    if (i < n) out[i] = 100.0f;
}

// ---------------- init: edge dtype detect (block 0) + cnt8 zeroing (blocks 1..) ----------------
__global__ void init_combo(const unsigned int* __restrict__ ei, int* __restrict__ flags,
                           unsigned* __restrict__ cnt8, int Mln) {
    if (blockIdx.x == 0) {
        if (threadIdx.x < 64) {
            int lane = threadIdx.x;
            int cz = 0;
            #pragma unroll
            for (int j = 0; j < 4; ++j) {
                int idx = lane * 4 + j;          // 0..255
                cz += (ei[2 * idx + 1] == 0u);   // odd words zero => int64 storage
            }
            #pragma unroll
            for (int off = 32; off; off >>= 1) cz += __shfl_down(cz, off);
            if (lane == 0) flags[0] = (cz > 200);
        }
    } else {
        int i = (blockIdx.x - 1) * 256 + threadIdx.x;
        if (i < Mln) cnt8[i] = 0u;
    }
}

// ---------------- CSR build ----------------
// XCD-sliced counters: cnt8[xcd][c]; workgroup-scope atomic. (R7-R9: agent-scope,
// padded, ILP'd, and XCD-sliced all measure the same ~41 µs / ~19 G ops/s — this
// atomic pass is a hard wall at HIP level; do not re-attack.)
__global__ void count_rank_xcd(const int* __restrict__ ei, unsigned* __restrict__ cnt8,
                               int* __restrict__ rank, int* __restrict__ c32,
                               int* __restrict__ r32, unsigned char* __restrict__ xcd8,
                               int E, int M, const int* __restrict__ flags) {
    int e = blockIdx.x * 256 + threadIdx.x;
    int xcd = get_xcd();
    if (e < E) {
        int r, c;
        if (flags[0]) { r = ei[2 * e]; c = ei[2 * E + 2 * e]; }
        else          { r = ei[e];     c = ei[E + e]; }
        c32[e] = c;
        r32[e] = r;
        xcd8[e] = (unsigned char)xcd;
        int rk = 0;
        if ((unsigned)c < (unsigned)M)
            rk = (int)__hip_atomic_fetch_add(&cnt8[(size_t)xcd * M + c], 1u,
                                             __ATOMIC_RELAXED, __HIP_MEMORY_SCOPE_WORKGROUP);
        rank[e] = rk;
    }
}

// per-256-block exclusive scan of totals; also emits per-XCD base offsets + totals
__global__ void scan_blocks_x(const unsigned* __restrict__ cnt8, unsigned* __restrict__ base8,
                              int* __restrict__ tot, int* __restrict__ excl,
                              int* __restrict__ bsum, int M) {
    int tid = threadIdx.x;
    int i = blockIdx.x * 256 + tid;
    int lane = tid & 63, wv = tid >> 6;
    __shared__ int ws[4];
    int v = 0;
    if (i < M) {
        unsigned run = 0;
        #pragma unroll
        for (int x = 0; x < 8; ++x) {
            unsigned cv = cnt8[(size_t)x * M + i];
            base8[(size_t)x * M + i] = run;
            run += cv;
        }
        v = (int)run;
        tot[i] = v;
    }
    int s = v;
    #pragma unroll
    for (int off = 1; off < 64; off <<= 1) {
        int t = __shfl_up(s, off);
        if (lane >= off) s += t;
    }
    if (lane == 63) ws[wv] = s;
    __syncthreads();
    if (tid == 0) { int a = 0; for (int q = 0; q < 4; ++q) { int t = ws[q]; ws[q] = a; a += t; } }
    __syncthreads();
    int ex = s - v + ws[wv];
    if (i < M) excl[i] = ex;
    if (tid == 255) bsum[blockIdx.x] = ex + v;
}

__global__ void scan_bsums(const int* __restrict__ bsum, int* __restrict__ boff,
                           int nb, int* __restrict__ colptr, int n) {
    int tid = threadIdx.x, lane = tid & 63, wv = tid >> 6;
    __shared__ int ws[4];
    __shared__ int carry;
    if (tid == 0) carry = 0;
    __syncthreads();
    for (int base = 0; base < nb; base += 256) {
        int i = base + tid;
        int v = (i < nb) ? bsum[i] : 0;
        int s = v;
        #pragma unroll
        for (int off = 1; off < 64; off <<= 1) {
            int t = __shfl_up(s, off);
            if (lane >= off) s += t;
        }
        if (lane == 63) ws[wv] = s;
        __syncthreads();
        if (tid == 0) { int a = carry; for (int q = 0; q < 4; ++q) { int t = ws[q]; ws[q] = a; a += t; } carry = a; }
        __syncthreads();
        int ex = s - v + ws[wv];
        if (i < nb) boff[i] = ex;
        __syncthreads();
    }
    if (tid == 0) colptr[n] = carry;
}

__global__ void scan_add_dinv(const int* __restrict__ excl, const int* __restrict__ boff,
                              const int* __restrict__ tot, int* __restrict__ colptr,
                              float* __restrict__ dinv, int n) {
    int i = blockIdx.x * 256 + threadIdx.x;
    if (i < n) {
        colptr[i] = excl[i] + boff[blockIdx.x];
        dinv[i] = rsqrtf((float)tot[i] + 1.0f);
    }
}

// ---------------- fused: single-pass CSR fill + x fp8 prescale + weight transposes ----------
// (R10: the 8-pass partitioned fill predates compact c32/r32 — it pulled rank/r32
//  lines 8x for sparse matches. Single coalesced pass reads each array once;
//  esrc stores are fire-and-forget scattered 4B writes.)
__global__ void fill_prep_fused(
    const int* __restrict__ c32, const int* __restrict__ r32,
    const unsigned char* __restrict__ xcd8, const unsigned* __restrict__ base8,
    const int* __restrict__ colptr, const int* __restrict__ rank,
    int* __restrict__ esrc, int E,
    const float* __restrict__ x, const float* __restrict__ dinv,
    unsigned char* __restrict__ xs8,
    const float* __restrict__ W1, const float* __restrict__ W2,
    const float* __restrict__ W3,
    unsigned short* __restrict__ Wt1, unsigned short* __restrict__ Wt2,
    unsigned short* __restrict__ Wt3,
    int M, int nfe, int nps)
{
    int b = (int)blockIdx.x;
    if (b < nfe) {
        // ---- single-pass CSR fill ----
        int e = b * 256 + threadIdx.x;
        if (e < E) {
            int c = c32[e];
            if ((unsigned)c < (unsigned)M) {
                int r = r32[e];
                if ((unsigned)r < (unsigned)M) {
                    int p = colptr[c] + (int)base8[(size_t)xcd8[e] * M + c] + rank[e];
                    if ((unsigned)p < (unsigned)E) esrc[p] = r;
                }
            }
        }
    } else if (b < nfe + nps) {
        // ---- x pre-scale -> fp8 (4 ch/thread) ----
        int i = (b - nfe) * 256 + threadIdx.x;
        if (i < M * 32) {
            int row = i >> 5;
            float dv = dinv[row];
            float4 v = *(const float4*)(x + (size_t)i * 4);
            unsigned u = __builtin_amdgcn_cvt_pk_fp8_f32(v.x * dv, v.y * dv, 0, false);
            u = __builtin_amdgcn_cvt_pk_fp8_f32(v.z * dv, v.w * dv, u, true);
            *(unsigned*)(xs8 + (size_t)i * 4) = u;
        }
    } else {
        // ---- weight transposes f32 -> bf16 (W^T layout) ----
        int i = (b - nfe - nps) * 256 + threadIdx.x;
        if (i < 32768) {                       // W1: 128x256
            int k = i >> 8, n = i & 255;
            Wt1[n * 128 + k] = f2bf_bits(W1[i]);
        } else if (i < 32768 + 65536) {        // W2: 256x256
            int j = i - 32768;
            int k = j >> 8, n = j & 255;
            Wt2[n * 256 + k] = f2bf_bits(W2[j]);
        } else if (i < 114688) {               // W3: 256x64
            int j = i - 98304;
            int k = j >> 6, n = j & 63;
            Wt3[n * 256 + k] = f2bf_bits(W3[j]);
        }
    }
}

// ---------------- tiled GEMM (bf16 MFMA), K-split staging ----------------
// EPI=0: Y(bf16) = dinv[m] * (A·B)
// EPI=1: Y(bf16) = sigmoid(A·B + bias[n])
// EPI=2: Y(fp8 e4m3) = dinv[m] * (A·B)    (row-major store)
template<int K, int BN, int NTOT, int EPI>
__global__ __launch_bounds__(256) void gemm_tile(
    const __bf16* __restrict__ A,
    const unsigned short* __restrict__ Bt,
    const float* __restrict__ dinv,
    const float* __restrict__ bias,
    void* __restrict__ Y,
    int M)
{
    constexpr int KS = (K > 128) ? 128 : K;   // staged chunk
    constexpr int KP = KS + 8;
    constexpr int NT = BN / 2 / 16;   // n-tiles per wave
    __shared__ unsigned short Bs[BN * KP];

    const int tid  = threadIdx.x;
    const int lane = tid & 63;
    const int wave = tid >> 6;        // 0..3
    const int wm   = wave >> 1;       // 0..1  row group
    const int wn   = wave & 1;        // 0..1  col group
    const int quad = lane >> 4;       // 0..3
    const int l16  = lane & 15;
    const int n0   = blockIdx.y * BN;

    int mrow[4];
#pragma unroll
    for (int mt = 0; mt < 4; ++mt) {
        int r = blockIdx.x * 128 + wm * 64 + mt * 16 + l16;
        mrow[mt] = (r < M) ? r : (M - 1);
    }

    f32x4_t acc[4][NT];
#pragma unroll
    for (int mt = 0; mt < 4; ++mt)
#pragma unroll
        for (int t = 0; t < NT; ++t) acc[mt][t] = (f32x4_t){0.f, 0.f, 0.f, 0.f};

    const unsigned short* BsW = &Bs[(wn * (BN / 2)) * KP];

    for (int kh = 0; kh < K; kh += KS) {
        constexpr int CH = BN * KS / 8;    // 16B chunks
        for (int idx = tid; idx < CH; idx += 256) {
            int n  = idx / (KS / 8);
            int k8 = idx - n * (KS / 8);
            uint4 v = *(const uint4*)(Bt + (size_t)(n0 + n) * K + kh + k8 * 8);
            *(uint4*)&Bs[n * KP + k8 * 8] = v;
        }
        __syncthreads();

#pragma unroll
        for (int kc = 0; kc < KS; kc += 32) {
            bf16x8_t a[4], b[NT];
#pragma unroll
            for (int mt = 0; mt < 4; ++mt)
                a[mt] = *(const bf16x8_t*)(A + (size_t)mrow[mt] * K + kh + kc + quad * 8);
#pragma unroll
            for (int t = 0; t < NT; ++t)
                b[t] = *(const bf16x8_t*)&BsW[(t * 16 + l16) * KP + kc + quad * 8];
#pragma unroll
            for (int mt = 0; mt < 4; ++mt)
#pragma unroll
                for (int t = 0; t < NT; ++t)
                    acc[mt][t] = __builtin_amdgcn_mfma_f32_16x16x32_bf16(a[mt], b[t], acc[mt][t], 0, 0, 0);
        }
        if (kh + KS < K) __syncthreads();
    }

    float bv[NT];
    if constexpr (EPI == 1) {
#pragma unroll
        for (int t = 0; t < NT; ++t)
            bv[t] = bias[n0 + wn * (BN / 2) + t * 16 + l16];
    }

#pragma unroll
    for (int mt = 0; mt < 4; ++mt) {
        int rowbase = blockIdx.x * 128 + wm * 64 + mt * 16 + quad * 4;
#pragma unroll
        for (int r = 0; r < 4; ++r) {
            int rrow = rowbase + r;
            if (rrow < M) {
                if constexpr (EPI == 0) {
                    float dv = dinv[rrow];
#pragma unroll
                    for (int t = 0; t < NT; ++t) {
                        int ccol = n0 + wn * (BN / 2) + t * 16 + l16;
                        ((__hip_bfloat16*)Y)[(size_t)rrow * NTOT + ccol] =
                            __float2bfloat16(acc[mt][t][r] * dv);
                    }
                } else if constexpr (EPI == 1) {
#pragma unroll
                    for (int t = 0; t < NT; ++t) {
                        int ccol = n0 + wn * (BN / 2) + t * 16 + l16;
                        float o = acc[mt][t][r] + bv[t];
                        o = 1.f / (1.f + __expf(-o));
                        ((__hip_bfloat16*)Y)[(size_t)rrow * NTOT + ccol] = __float2bfloat16(o);
                    }
                } else {
                    float dv = dinv[rrow];
#pragma unroll
                    for (int t = 0; t < NT; ++t) {
                        int ccol = n0 + wn * (BN / 2) + t * 16 + l16;
                        float o = acc[mt][t][r] * dv;
                        int pk = __builtin_amdgcn_cvt_pk_fp8_f32(o, o, 0, false);
                        ((unsigned char*)Y)[(size_t)rrow * NTOT + ccol] = (unsigned char)(pk & 0xff);
                    }
                }
            }
        }
    }
}

// ================= aggregations =================
// fp8 C=256 (layer 2): wave covers one 256B row, 4B/lane. 2-deep x 8-wide pipeline.
// (Best measured: 42.4 µs @ 83 MB compulsory fetch — the ~2 TB/s L3-random wall.
//  Chunk-split (R5/R6) cut fetch to 61 MB but cost 57-61 µs. Do not re-split.)
__global__ __launch_bounds__(256) void aggregate_fp8_v4(
    const unsigned char* __restrict__ Y8,
    const int* __restrict__ colptr,
    const int* __restrict__ esrc,
    const float* __restrict__ dinv,
    const float* __restrict__ bias,
    unsigned short* __restrict__ H,
    int M, int Etot)
{
    const int lane = threadIdx.x & 63;
    const int wave = threadIdx.x >> 6;
    int node = blockIdx.x * 4 + wave;
    if (node >= M) return;

    int s = colptr[node];
    int e = colptr[node + 1];
    if (s < 0) s = 0;
    if (e > Etot) e = Etot;
    if (e < s) e = s;
    int n = e - s;

    const char* Yb = (const char*)Y8;
    const unsigned lb = (unsigned)(lane * 4);

    unsigned su = *(const unsigned*)(Yb + (((unsigned)node) << 8) + lb);

    f32x2_t a0 = {0.f, 0.f}, a1 = {0.f, 0.f};

    auto gather8 = [&](unsigned* u, int base) {
        #pragma unroll
        for (int k = 0; k < 8; ++k) {
            unsigned off = (((unsigned)esrc[s + base + k]) << 8) + lb;
            u[k] = *(const unsigned*)(Yb + off);
        }
    };
    auto acc8 = [&](const unsigned* u) {
        #pragma unroll
        for (int k = 0; k < 8; ++k) {
            a0 += __builtin_amdgcn_cvt_pk_f32_fp8(u[k], false);
            a1 += __builtin_amdgcn_cvt_pk_f32_fp8(u[k], true);
        }
    };

    unsigned ua[8], ub[8];
    int NB = n >> 3;
    if (NB > 0) {
        gather8(ua, 0);
        int i = 1;
        for (; i + 1 < NB; i += 2) {
            gather8(ub, i << 3);
            acc8(ua);
            gather8(ua, (i + 1) << 3);
            acc8(ub);
        }
        if (i < NB) {
            gather8(ub, i << 3);
            acc8(ua);
            acc8(ub);
        } else {
            acc8(ua);
        }
    }
    #pragma unroll 2
    for (int t = NB << 3; t < n; ++t) {
        unsigned off = (((unsigned)esrc[s + t]) << 8) + lb;
        unsigned u = *(const unsigned*)(Yb + off);
        a0 += __builtin_amdgcn_cvt_pk_f32_fp8(u, false);
        a1 += __builtin_amdgcn_cvt_pk_f32_fp8(u, true);
    }
    a0 += __builtin_amdgcn_cvt_pk_f32_fp8(su, false);
    a1 += __builtin_amdgcn_cvt_pk_f32_fp8(su, true);

    float dv = dinv[node];
    float4 bv = *(const float4*)(bias + lane * 4);
    float o0 = a0[0] * dv + bv.x;
    float o1 = a0[1] * dv + bv.y;
    float o2 = a1[0] * dv + bv.z;
    float o3 = a1[1] * dv + bv.w;
    o0 = 1.f / (1.f + __expf(-o0));
    o1 = 1.f / (1.f + __expf(-o1));
    o2 = 1.f / (1.f + __expf(-o2));
    o3 = 1.f / (1.f + __expf(-o3));
    uint2 st;
    st.x = (unsigned)f2bf_bits(o0) | ((unsigned)f2bf_bits(o1) << 16);
    st.y = (unsigned)f2bf_bits(o2) | ((unsigned)f2bf_bits(o3) << 16);
    *(uint2*)(H + (size_t)node * 256 + lane * 4) = st;
}

// fp8 C=128 (layer-1 xs aggregation): 128B rows, uint2/16-lane, batch-8 ping-pong.
__global__ __launch_bounds__(256) void aggregate_xs8b(
    const unsigned char* __restrict__ X8,
    const int* __restrict__ colptr,
    const int* __restrict__ esrc,
    const float* __restrict__ dinv,
    unsigned short* __restrict__ xa,
    int M, int Etot)
{
    const int lane = threadIdx.x & 63;
    const int wave = threadIdx.x >> 6;
    const int l4 = lane & 15;
    const int g4 = lane >> 4;
    int node = blockIdx.x * 4 + wave;
    if (node >= M) return;

    int s = colptr[node];
    int e = colptr[node + 1];
    if (s < 0) s = 0;
    if (e > Etot) e = Etot;
    if (e < s) e = s;
    int n = e - s;

    const char* Yb = (const char*)X8;
    const unsigned lb = (unsigned)(l4 * 8);

    uint2 su = {0u, 0u};
    if (g4 == 0) su = *(const uint2*)(Yb + ((unsigned)node) * 128u + lb);

    f32x2_t a0 = {0.f, 0.f}, a1 = {0.f, 0.f}, a2 = {0.f, 0.f}, a3 = {0.f, 0.f};

    auto gat = [&](uint2* u, int base) {
        u[0] = *(const uint2*)(Yb + ((unsigned)esrc[s + base + g4]) * 128u + lb);
        u[1] = *(const uint2*)(Yb + ((unsigned)esrc[s + base + 4 + g4]) * 128u + lb);
    };
    auto acc = [&](const uint2* u) {
        #pragma unroll
        for (int k = 0; k < 2; ++k) {
            a0 += __builtin_amdgcn_cvt_pk_f32_fp8(u[k].x, false);
            a1 += __builtin_amdgcn_cvt_pk_f32_fp8(u[k].x, true);
            a2 += __builtin_amdgcn_cvt_pk_f32_fp8(u[k].y, false);
            a3 += __builtin_amdgcn_cvt_pk_f32_fp8(u[k].y, true);
        }
    };

    uint2 ua[2], ub[2];
    int NB = n >> 3;
    if (NB > 0) {
        gat(ua, 0);
        int i = 1;
        for (; i + 1 < NB; i += 2) {
            gat(ub, i << 3); acc(ua);
            gat(ua, (i + 1) << 3); acc(ub);
        }
        if (i < NB) { gat(ub, i << 3); acc(ua); acc(ub); }
        else acc(ua);
    }
    for (int t = NB << 3; t < n; t += 4) {
        if (t + g4 < n) {
            uint2 u = *(const uint2*)(Yb + ((unsigned)esrc[s + t + g4]) * 128u + lb);
            a0 += __builtin_amdgcn_cvt_pk_f32_fp8(u.x, false);
            a1 += __builtin_amdgcn_cvt_pk_f32_fp8(u.x, true);
            a2 += __builtin_amdgcn_cvt_pk_f32_fp8(u.y, false);
            a3 += __builtin_amdgcn_cvt_pk_f32_fp8(u.y, true);
        }
    }
    if (g4 == 0) {
        a0 += __builtin_amdgcn_cvt_pk_f32_fp8(su.x, false);
        a1 += __builtin_amdgcn_cvt_pk_f32_fp8(su.x, true);
        a2 += __builtin_amdgcn_cvt_pk_f32_fp8(su.y, false);
        a3 += __builtin_amdgcn_cvt_pk_f32_fp8(su.y, true);
    }

    #pragma unroll
    for (int off = 16; off < 64; off <<= 1) {
        a0[0] += __shfl_xor(a0[0], off); a0[1] += __shfl_xor(a0[1], off);
        a1[0] += __shfl_xor(a1[0], off); a1[1] += __shfl_xor(a1[1], off);
        a2[0] += __shfl_xor(a2[0], off); a2[1] += __shfl_xor(a2[1], off);
        a3[0] += __shfl_xor(a3[0], off); a3[1] += __shfl_xor(a3[1], off);
    }

    if (g4 == 0) {   // channels [l4*8, +8)
        float dv = dinv[node];
        uint4 st;
        st.x = (unsigned)f2bf_bits(a0[0] * dv) | ((unsigned)f2bf_bits(a0[1] * dv) << 16);
        st.y = (unsigned)f2bf_bits(a1[0] * dv) | ((unsigned)f2bf_bits(a1[1] * dv) << 16);
        st.z = (unsigned)f2bf_bits(a2[0] * dv) | ((unsigned)f2bf_bits(a2[1] * dv) << 16);
        st.w = (unsigned)f2bf_bits(a3[0] * dv) | ((unsigned)f2bf_bits(a3[1] * dv) << 16);
        *(uint4*)(xa + (size_t)node * 128 + l4 * 8) = st;
    }
}

// bf16 C=64, f32 out + bias (layer 3): 128B rows, uint2/16-lane, batch-8 ping-pong.
__global__ __launch_bounds__(256) void aggregate_bf16_64_v5(
    const unsigned short* __restrict__ Yin,
    const int* __restrict__ colptr,
    const int* __restrict__ esrc,
    const float* __restrict__ dinv,
    const float* __restrict__ bias,
    float* __restrict__ out,
    int M, int Etot)
{
    const int lane = threadIdx.x & 63;
    const int wave = threadIdx.x >> 6;
    const int l4 = lane & 15;
    const int g4 = lane >> 4;
    int node = blockIdx.x * 4 + wave;
    if (node >= M) return;

    int s = colptr[node];
    int e = colptr[node + 1];
    if (s < 0) s = 0;
    if (e > Etot) e = Etot;
    if (e < s) e = s;
    int n = e - s;

    const char* Yb = (const char*)Yin;
    const unsigned lb = (unsigned)(l4 * 8);

    uint2 su = {0u, 0u};
    if (g4 == 0) su = *(const uint2*)(Yb + ((unsigned)node) * 128u + lb);

    f32x2_t a0 = {0.f, 0.f}, a1 = {0.f, 0.f};

    auto gat = [&](uint2* u, int base) {
        u[0] = *(const uint2*)(Yb + ((unsigned)esrc[s + base + g4]) * 128u + lb);
        u[1] = *(const uint2*)(Yb + ((unsigned)esrc[s + base + 4 + g4]) * 128u + lb);
    };
    auto acc = [&](const uint2* u) {
        #pragma unroll
        for (int k = 0; k < 2; ++k) {
            a0 += unpack_bf2(u[k].x);
            a1 += unpack_bf2(u[k].y);
        }
    };

    uint2 ua[2], ub[2];
    int NB = n >> 3;
    if (NB > 0) {
        gat(ua, 0);
        int i = 1;
        for (; i + 1 < NB; i += 2) {
            gat(ub, i << 3); acc(ua);
            gat(ua, (i + 1) << 3); acc(ub);
        }
        if (i < NB) { gat(ub, i << 3); acc(ua); acc(ub); }
        else acc(ua);
    }
    for (int t = NB << 3; t < n; t += 4) {
        if (t + g4 < n) {
            uint2 u = *(const uint2*)(Yb + ((unsigned)esrc[s + t + g4]) * 128u + lb);
            a0 += unpack_bf2(u.x);
            a1 += unpack_bf2(u.y);
        }
    }
    if (g4 == 0) {
        a0 += unpack_bf2(su.x);
        a1 += unpack_bf2(su.y);
    }

    #pragma unroll
    for (int off = 16; off < 64; off <<= 1) {
        a0[0] += __shfl_xor(a0[0], off); a0[1] += __shfl_xor(a0[1], off);
        a1[0] += __shfl_xor(a1[0], off); a1[1] += __shfl_xor(a1[1], off);
    }

    if (g4 == 0) {   // channels [l4*4, +4)
        float dv = dinv[node];
        float4 bv = *(const float4*)(bias + l4 * 4);
        float4 st;
        st.x = a0[0] * dv + bv.x;
        st.y = a0[1] * dv + bv.y;
        st.z = a1[0] * dv + bv.z;
        st.w = a1[1] * dv + bv.w;
        *(float4*)(out + (size_t)node * 64 + l4 * 4) = st;
    }
}

// ---------------- launch ----------------

extern "C" void kernel_launch(void* const* d_in, const int* in_sizes, int n_in,
                              void* d_out, int out_size, void* d_ws, size_t ws_size,
                              hipStream_t stream)
{
    int iEI = 2, iW1 = 3, iB1 = 4, iW2 = 5, iB2 = 6, iW3 = 7, iB3 = 8;
    if (n_in == 8) { iEI = 1; iW1 = 2; iB1 = 3; iW2 = 4; iB2 = 5; iW3 = 6; iB3 = 7; }

    const float* x  = (const float*)d_in[0];
    const int* ei   = (const int*)d_in[iEI];
    const float* W1 = (const float*)d_in[iW1];
    const float* b1 = (const float*)d_in[iB1];
    const float* W2 = (const float*)d_in[iW2];
    const float* b2 = (const float*)d_in[iB2];
    const float* W3 = (const float*)d_in[iW3];
    const float* b3 = (const float*)d_in[iB3];

    const int M = in_sizes[0] / 128;     // 50000
    const int E = in_sizes[iEI] / 2;     // 800000
    const int NB = (M + 255) / 256;      // scan blocks

    auto rnd = [](size_t b) { return (b + 255) & ~(size_t)255; };
    size_t needed = rnd(64 * 4)                          // flags
                  + rnd((size_t)M * 4)                   // dinv
                  + rnd((size_t)M * 32) * 2              // cnt8, base8 (8 XCD slices)
                  + rnd((size_t)M * 4)                   // tot
                  + rnd((size_t)(M + 1) * 4)             // colptr
                  + rnd((size_t)M * 4)                   // excl
                  + rnd((size_t)(NB + 1) * 4) * 2        // bsum, boff
                  + rnd((size_t)E * 4) * 4               // esrc, rank, c32, r32
                  + rnd((size_t)E)                       // xcd8
                  + rnd((size_t)256 * 128 * 2)           // Wt1
                  + rnd((size_t)256 * 256 * 2)           // Wt2
                  + rnd((size_t)64 * 256 * 2)            // Wt3
                  + rnd((size_t)M * 256 * 2) * 2;        // ybuf, hbuf
    if (ws_size < needed) {
        sentinel_fill<<<(out_size + 255) / 256, 256, 0, stream>>>((float*)d_out, out_size);
        return;
    }

    char* p = (char*)d_ws;
    auto alloc = [&](size_t bytes) {
        char* r = p;
        p += (bytes + 255) & ~(size_t)255;
        return r;
    };
    int* flags  = (int*)alloc(64 * 4);
    float* dinv = (float*)alloc((size_t)M * 4);
    unsigned* cnt8  = (unsigned*)alloc((size_t)M * 32);
    unsigned* base8 = (unsigned*)alloc((size_t)M * 32);
    int* tot    = (int*)alloc((size_t)M * 4);
    int* colptr = (int*)alloc((size_t)(M + 1) * 4);
    int* excl   = (int*)alloc((size_t)M * 4);
    int* bsum   = (int*)alloc((size_t)(NB + 1) * 4);
    int* boff   = (int*)alloc((size_t)(NB + 1) * 4);
    int* esrc   = (int*)alloc((size_t)E * 4);
    int* rank   = (int*)alloc((size_t)E * 4);
    int* c32    = (int*)alloc((size_t)E * 4);
    int* r32    = (int*)alloc((size_t)E * 4);
    unsigned char* xcd8 = (unsigned char*)alloc((size_t)E);
    unsigned short* Wt1 = (unsigned short*)alloc((size_t)256 * 128 * 2);
    unsigned short* Wt2 = (unsigned short*)alloc((size_t)256 * 256 * 2);
    unsigned short* Wt3 = (unsigned short*)alloc((size_t)64 * 256 * 2);
    __hip_bfloat16* ybuf = (__hip_bfloat16*)alloc((size_t)M * 256 * 2);
    __hip_bfloat16* hbuf = (__hip_bfloat16*)alloc((size_t)M * 256 * 2);

    // region reuse inside ybuf:
    unsigned char* xs8 = (unsigned char*)ybuf;                     // M x 128 fp8 (6.4MB)
    unsigned short* xa = (unsigned short*)ybuf + (size_t)M * 128;  // M x 128 bf16 (at +12.8MB)
    unsigned char*  y8 = (unsigned char*)ybuf;                     // M x 256 fp8 row-major (after xs8 dead)

    // init: detect dtype (block 0) + zero cnt8 (blocks 1..)
    int Mln = M * 8;
    init_combo<<<(Mln + 255) / 256 + 1, 256, 0, stream>>>(
        (const unsigned int*)ei, flags, cnt8, Mln);

    count_rank_xcd<<<(E + 255) / 256, 256, 0, stream>>>(
        ei, cnt8, rank, c32, r32, xcd8, E, M, flags);
    scan_blocks_x<<<NB, 256, 0, stream>>>(cnt8, base8, tot, excl, bsum, M);
    scan_bsums<<<1, 256, 0, stream>>>(bsum, boff, NB, colptr, M);
    scan_add_dinv<<<NB, 256, 0, stream>>>(excl, boff, tot, colptr, dinv, M);

    int gmb = (M + 127) / 128;           // 391
    int ga  = (M + 3) / 4;               // 12500
    int nfe = (E + 255) / 256;           // fill blocks (single pass)
    int nps = (M * 32 + 255) / 256;      // prescale blocks (4 ch/thread)

    // fused: single-pass CSR fill + fp8 prescale of x + weight transposes
    fill_prep_fused<<<nfe + nps + 448, 256, 0, stream>>>(
        c32, r32, xcd8, base8, colptr, rank, esrc, E,
        x, dinv, xs8, W1, W2, W3, Wt1, Wt2, Wt3, M, nfe, nps);

    // Layer 1: aggregate fp8 xs (S·x), then GEMM with fused bias+sigmoid
    aggregate_xs8b<<<ga, 256, 0, stream>>>(
        xs8, colptr, esrc, dinv, xa, M, E);
    gemm_tile<128, 128, 256, 1><<<dim3(gmb, 2), 256, 0, stream>>>(
        (const __bf16*)xa, Wt1, dinv, b1, hbuf, M);
    // Layer 2: GEMM -> fp8 table (row-major), fp8 gather aggregate -> bf16 h2
    gemm_tile<256, 128, 256, 2><<<dim3(gmb, 2), 256, 0, stream>>>(
        (const __bf16*)hbuf, Wt2, dinv, b2, y8, M);
    aggregate_fp8_v4<<<ga, 256, 0, stream>>>(
        y8, colptr, esrc, dinv, b2, (unsigned short*)hbuf, M, E);
    // Layer 3: bf16
    gemm_tile<256, 64, 64, 0><<<dim3(gmb, 1), 256, 0, stream>>>(
        (const __bf16*)hbuf, Wt3, dinv, b3, ybuf, M);
    aggregate_bf16_64_v5<<<ga, 256, 0, stream>>>(
        (const unsigned short*)ybuf, colptr, esrc, dinv, b3, (float*)d_out, M, E);
}

// Round 11
// 314.341 us; speedup vs baseline: 1.0406x; 1.0043x over previous
//
#include <hip/hip_runtime.h>
#include <hip/hip_bf16.h>

typedef __bf16 bf16x8_t __attribute__((ext_vector_type(8)));
typedef float f32x4_t __attribute__((ext_vector_type(4)));
typedef float f32x2_t __attribute__((ext_vector_type(2)));

__device__ __forceinline__ float bits2f(unsigned int u) {
    union { unsigned int u; float f; } c; c.u = u; return c.f;
}
__device__ __forceinline__ unsigned short f2bf_bits(float f) {
    __hip_bfloat16 h = __float2bfloat16(f);
    return __builtin_bit_cast(unsigned short, h);
}
__device__ __forceinline__ f32x2_t unpack_bf2(unsigned int u) {
    return (f32x2_t){bits2f(u << 16), bits2f(u & 0xffff0000u)};
}
// XCD id (0..7) — HW_REG_XCC_ID, wave-uniform; workgroup lives on one CU/XCD.
__device__ __forceinline__ int get_xcd() {
    unsigned v;
    asm volatile("s_getreg_b32 %0, hwreg(HW_REG_XCC_ID)" : "=s"(v));
    return (int)(v & 7);
}

// ---------------- sentinel (ws too small) ----------------
__global__ void sentinel_fill(float* __restrict__ out, int n) {
    int i = blockIdx.x * blockDim.x + threadIdx.x;
    if (i < n) out[i] = 100.0f;
}

// ---------------- zero cnt8 ----------------
__global__ void init_zero(unsigned* __restrict__ cnt8, int Mln) {
    int i = blockIdx.x * 256 + threadIdx.x;
    if (i < Mln) cnt8[i] = 0u;
}

// ---------------- CSR build ----------------
// XCD-sliced counters: cnt8[xcd][c]; workgroup-scope atomic. (R7-R9: agent-scope,
// padded, ILP'd, and XCD-sliced all measure the same ~41 µs / ~19 G ops/s — this
// atomic pass is a hard wall at HIP level; do not re-attack.)
// Dtype detect (int64 vs int32 edge_index) is inlined per-block from the first
// 256 entries (L2-hot) — removes the separate detect dispatch + flags dependency.
__global__ void count_rank_xcd(const int* __restrict__ ei, unsigned* __restrict__ cnt8,
                               int* __restrict__ rank, int* __restrict__ c32,
                               int* __restrict__ r32, unsigned char* __restrict__ xcd8,
                               int E, int M) {
    __shared__ int sflag;
    if (threadIdx.x < 64) {
        int lane = threadIdx.x;
        int cz = 0;
        #pragma unroll
        for (int j = 0; j < 4; ++j) {
            int idx = lane * 4 + j;                                // 0..255
            cz += (((const unsigned*)ei)[2 * idx + 1] == 0u);      // odd words zero => int64
        }
        #pragma unroll
        for (int off = 32; off; off >>= 1) cz += __shfl_down(cz, off);
        if (lane == 0) sflag = (cz > 200);
    }
    __syncthreads();
    bool f64 = sflag != 0;

    int e = blockIdx.x * 256 + threadIdx.x;
    int xcd = get_xcd();
    if (e < E) {
        int r, c;
        if (f64) { r = ei[2 * e]; c = ei[2 * E + 2 * e]; }
        else     { r = ei[e];     c = ei[E + e]; }
        c32[e] = c;
        r32[e] = r;
        xcd8[e] = (unsigned char)xcd;
        int rk = 0;
        if ((unsigned)c < (unsigned)M)
            rk = (int)__hip_atomic_fetch_add(&cnt8[(size_t)xcd * M + c], 1u,
                                             __ATOMIC_RELAXED, __HIP_MEMORY_SCOPE_WORKGROUP);
        rank[e] = rk;
    }
}

// per-256-block exclusive scan of totals; also emits per-XCD base offsets + totals
__global__ void scan_blocks_x(const unsigned* __restrict__ cnt8, unsigned* __restrict__ base8,
                              int* __restrict__ tot, int* __restrict__ excl,
                              int* __restrict__ bsum, int M) {
    int tid = threadIdx.x;
    int i = blockIdx.x * 256 + tid;
    int lane = tid & 63, wv = tid >> 6;
    __shared__ int ws[4];
    int v = 0;
    if (i < M) {
        unsigned run = 0;
        #pragma unroll
        for (int x = 0; x < 8; ++x) {
            unsigned cv = cnt8[(size_t)x * M + i];
            base8[(size_t)x * M + i] = run;
            run += cv;
        }
        v = (int)run;
        tot[i] = v;
    }
    int s = v;
    #pragma unroll
    for (int off = 1; off < 64; off <<= 1) {
        int t = __shfl_up(s, off);
        if (lane >= off) s += t;
    }
    if (lane == 63) ws[wv] = s;
    __syncthreads();
    if (tid == 0) { int a = 0; for (int q = 0; q < 4; ++q) { int t = ws[q]; ws[q] = a; a += t; } }
    __syncthreads();
    int ex = s - v + ws[wv];
    if (i < M) excl[i] = ex;
    if (tid == 255) bsum[blockIdx.x] = ex + v;
}

// fold of old scan_bsums + scan_add_dinv: each block redundantly reduces
// bsum[0..blockIdx) (<=255 L2-hot ints per thread-strided load) — removes one
// dispatch + its launch gap (R11).
__global__ void scan_add_dinv2(const int* __restrict__ excl, const int* __restrict__ bsum,
                               const int* __restrict__ tot, int* __restrict__ colptr,
                               float* __restrict__ dinv, int n, int nb) {
    int tid = threadIdx.x, lane = tid & 63, wv = tid >> 6;
    __shared__ int ws[4];
    __shared__ int s_off;
    int v = 0;
    for (int b = tid; b < (int)blockIdx.x; b += 256) v += bsum[b];
    #pragma unroll
    for (int off = 32; off; off >>= 1) v += __shfl_down(v, off);
    if (lane == 0) ws[wv] = v;
    __syncthreads();
    if (tid == 0) s_off = ws[0] + ws[1] + ws[2] + ws[3];
    __syncthreads();
    int off0 = s_off;
    int i = blockIdx.x * 256 + tid;
    if (i < n) {
        colptr[i] = excl[i] + off0;
        dinv[i] = rsqrtf((float)tot[i] + 1.0f);
    }
    if ((int)blockIdx.x == nb - 1 && tid == 0)
        colptr[n] = off0 + bsum[nb - 1];
}

// ---------------- fused: single-pass CSR fill + x fp8 prescale + weight transposes ----------
__global__ void fill_prep_fused(
    const int* __restrict__ c32, const int* __restrict__ r32,
    const unsigned char* __restrict__ xcd8, const unsigned* __restrict__ base8,
    const int* __restrict__ colptr, const int* __restrict__ rank,
    int* __restrict__ esrc, int E,
    const float* __restrict__ x, const float* __restrict__ dinv,
    unsigned char* __restrict__ xs8,
    const float* __restrict__ W1, const float* __restrict__ W2,
    const float* __restrict__ W3,
    unsigned short* __restrict__ Wt1, unsigned short* __restrict__ Wt2,
    unsigned short* __restrict__ Wt3,
    int M, int nfe, int nps)
{
    int b = (int)blockIdx.x;
    if (b < nfe) {
        // ---- single-pass CSR fill ----
        int e = b * 256 + threadIdx.x;
        if (e < E) {
            int c = c32[e];
            if ((unsigned)c < (unsigned)M) {
                int r = r32[e];
                if ((unsigned)r < (unsigned)M) {
                    int p = colptr[c] + (int)base8[(size_t)xcd8[e] * M + c] + rank[e];
                    if ((unsigned)p < (unsigned)E) esrc[p] = r;
                }
            }
        }
    } else if (b < nfe + nps) {
        // ---- x pre-scale -> fp8 (4 ch/thread) ----
        int i = (b - nfe) * 256 + threadIdx.x;
        if (i < M * 32) {
            int row = i >> 5;
            float dv = dinv[row];
            float4 v = *(const float4*)(x + (size_t)i * 4);
            unsigned u = __builtin_amdgcn_cvt_pk_fp8_f32(v.x * dv, v.y * dv, 0, false);
            u = __builtin_amdgcn_cvt_pk_fp8_f32(v.z * dv, v.w * dv, u, true);
            *(unsigned*)(xs8 + (size_t)i * 4) = u;
        }
    } else {
        // ---- weight transposes f32 -> bf16 (W^T layout) ----
        int i = (b - nfe - nps) * 256 + threadIdx.x;
        if (i < 32768) {                       // W1: 128x256
            int k = i >> 8, n = i & 255;
            Wt1[n * 128 + k] = f2bf_bits(W1[i]);
        } else if (i < 32768 + 65536) {        // W2: 256x256
            int j = i - 32768;
            int k = j >> 8, n = j & 255;
            Wt2[n * 256 + k] = f2bf_bits(W2[j]);
        } else if (i < 114688) {               // W3: 256x64
            int j = i - 98304;
            int k = j >> 6, n = j & 63;
            Wt3[n * 256 + k] = f2bf_bits(W3[j]);
        }
    }
}

// ---------------- tiled GEMM (bf16 MFMA), K-split staging ----------------
// EPI=0: Y(bf16) = dinv[m] * (A·B)
// EPI=1: Y(bf16) = sigmoid(A·B + bias[n])
// EPI=2: Y(fp8 e4m3) = dinv[m] * (A·B)    (row-major store)
template<int K, int BN, int NTOT, int EPI>
__global__ __launch_bounds__(256) void gemm_tile(
    const __bf16* __restrict__ A,
    const unsigned short* __restrict__ Bt,
    const float* __restrict__ dinv,
    const float* __restrict__ bias,
    void* __restrict__ Y,
    int M)
{
    constexpr int KS = (K > 128) ? 128 : K;   // staged chunk
    constexpr int KP = KS + 8;
    constexpr int NT = BN / 2 / 16;   // n-tiles per wave
    __shared__ unsigned short Bs[BN * KP];

    const int tid  = threadIdx.x;
    const int lane = tid & 63;
    const int wave = tid >> 6;        // 0..3
    const int wm   = wave >> 1;       // 0..1  row group
    const int wn   = wave & 1;        // 0..1  col group
    const int quad = lane >> 4;       // 0..3
    const int l16  = lane & 15;
    const int n0   = blockIdx.y * BN;

    int mrow[4];
#pragma unroll
    for (int mt = 0; mt < 4; ++mt) {
        int r = blockIdx.x * 128 + wm * 64 + mt * 16 + l16;
        mrow[mt] = (r < M) ? r : (M - 1);
    }

    f32x4_t acc[4][NT];
#pragma unroll
    for (int mt = 0; mt < 4; ++mt)
#pragma unroll
        for (int t = 0; t < NT; ++t) acc[mt][t] = (f32x4_t){0.f, 0.f, 0.f, 0.f};

    const unsigned short* BsW = &Bs[(wn * (BN / 2)) * KP];

    for (int kh = 0; kh < K; kh += KS) {
        constexpr int CH = BN * KS / 8;    // 16B chunks
        for (int idx = tid; idx < CH; idx += 256) {
            int n  = idx / (KS / 8);
            int k8 = idx - n * (KS / 8);
            uint4 v = *(const uint4*)(Bt + (size_t)(n0 + n) * K + kh + k8 * 8);
            *(uint4*)&Bs[n * KP + k8 * 8] = v;
        }
        __syncthreads();

#pragma unroll
        for (int kc = 0; kc < KS; kc += 32) {
            bf16x8_t a[4], b[NT];
#pragma unroll
            for (int mt = 0; mt < 4; ++mt)
                a[mt] = *(const bf16x8_t*)(A + (size_t)mrow[mt] * K + kh + kc + quad * 8);
#pragma unroll
            for (int t = 0; t < NT; ++t)
                b[t] = *(const bf16x8_t*)&BsW[(t * 16 + l16) * KP + kc + quad * 8];
#pragma unroll
            for (int mt = 0; mt < 4; ++mt)
#pragma unroll
                for (int t = 0; t < NT; ++t)
                    acc[mt][t] = __builtin_amdgcn_mfma_f32_16x16x32_bf16(a[mt], b[t], acc[mt][t], 0, 0, 0);
        }
        if (kh + KS < K) __syncthreads();
    }

    float bv[NT];
    if constexpr (EPI == 1) {
#pragma unroll
        for (int t = 0; t < NT; ++t)
            bv[t] = bias[n0 + wn * (BN / 2) + t * 16 + l16];
    }

#pragma unroll
    for (int mt = 0; mt < 4; ++mt) {
        int rowbase = blockIdx.x * 128 + wm * 64 + mt * 16 + quad * 4;
#pragma unroll
        for (int r = 0; r < 4; ++r) {
            int rrow = rowbase + r;
            if (rrow < M) {
                if constexpr (EPI == 0) {
                    float dv = dinv[rrow];
#pragma unroll
                    for (int t = 0; t < NT; ++t) {
                        int ccol = n0 + wn * (BN / 2) + t * 16 + l16;
                        ((__hip_bfloat16*)Y)[(size_t)rrow * NTOT + ccol] =
                            __float2bfloat16(acc[mt][t][r] * dv);
                    }
                } else if constexpr (EPI == 1) {
#pragma unroll
                    for (int t = 0; t < NT; ++t) {
                        int ccol = n0 + wn * (BN / 2) + t * 16 + l16;
                        float o = acc[mt][t][r] + bv[t];
                        o = 1.f / (1.f + __expf(-o));
                        ((__hip_bfloat16*)Y)[(size_t)rrow * NTOT + ccol] = __float2bfloat16(o);
                    }
                } else {
                    float dv = dinv[rrow];
#pragma unroll
                    for (int t = 0; t < NT; ++t) {
                        int ccol = n0 + wn * (BN / 2) + t * 16 + l16;
                        float o = acc[mt][t][r] * dv;
                        int pk = __builtin_amdgcn_cvt_pk_fp8_f32(o, o, 0, false);
                        ((unsigned char*)Y)[(size_t)rrow * NTOT + ccol] = (unsigned char)(pk & 0xff);
                    }
                }
            }
        }
    }
}

// ================= aggregations =================
// fp8 C=256 (layer 2): wave covers one 256B row, 4B/lane. 2-deep x 8-wide pipeline.
// (Best measured: 42.4 µs @ 83 MB compulsory fetch — the ~2 TB/s L3-random wall.
//  Chunk-split (R5/R6) cut fetch to 61 MB but cost 57-61 µs. Do not re-split.)
__global__ __launch_bounds__(256) void aggregate_fp8_v4(
    const unsigned char* __restrict__ Y8,
    const int* __restrict__ colptr,
    const int* __restrict__ esrc,
    const float* __restrict__ dinv,
    const float* __restrict__ bias,
    unsigned short* __restrict__ H,
    int M, int Etot)
{
    const int lane = threadIdx.x & 63;
    const int wave = threadIdx.x >> 6;
    int node = blockIdx.x * 4 + wave;
    if (node >= M) return;

    int s = colptr[node];
    int e = colptr[node + 1];
    if (s < 0) s = 0;
    if (e > Etot) e = Etot;
    if (e < s) e = s;
    int n = e - s;

    const char* Yb = (const char*)Y8;
    const unsigned lb = (unsigned)(lane * 4);

    unsigned su = *(const unsigned*)(Yb + (((unsigned)node) << 8) + lb);

    f32x2_t a0 = {0.f, 0.f}, a1 = {0.f, 0.f};

    auto gather8 = [&](unsigned* u, int base) {
        #pragma unroll
        for (int k = 0; k < 8; ++k) {
            unsigned off = (((unsigned)esrc[s + base + k]) << 8) + lb;
            u[k] = *(const unsigned*)(Yb + off);
        }
    };
    auto acc8 = [&](const unsigned* u) {
        #pragma unroll
        for (int k = 0; k < 8; ++k) {
            a0 += __builtin_amdgcn_cvt_pk_f32_fp8(u[k], false);
            a1 += __builtin_amdgcn_cvt_pk_f32_fp8(u[k], true);
        }
    };

    unsigned ua[8], ub[8];
    int NB = n >> 3;
    if (NB > 0) {
        gather8(ua, 0);
        int i = 1;
        for (; i + 1 < NB; i += 2) {
            gather8(ub, i << 3);
            acc8(ua);
            gather8(ua, (i + 1) << 3);
            acc8(ub);
        }
        if (i < NB) {
            gather8(ub, i << 3);
            acc8(ua);
            acc8(ub);
        } else {
            acc8(ua);
        }
    }
    #pragma unroll 2
    for (int t = NB << 3; t < n; ++t) {
        unsigned off = (((unsigned)esrc[s + t]) << 8) + lb;
        unsigned u = *(const unsigned*)(Yb + off);
        a0 += __builtin_amdgcn_cvt_pk_f32_fp8(u, false);
        a1 += __builtin_amdgcn_cvt_pk_f32_fp8(u, true);
    }
    a0 += __builtin_amdgcn_cvt_pk_f32_fp8(su, false);
    a1 += __builtin_amdgcn_cvt_pk_f32_fp8(su, true);

    float dv = dinv[node];
    float4 bv = *(const float4*)(bias + lane * 4);
    float o0 = a0[0] * dv + bv.x;
    float o1 = a0[1] * dv + bv.y;
    float o2 = a1[0] * dv + bv.z;
    float o3 = a1[1] * dv + bv.w;
    o0 = 1.f / (1.f + __expf(-o0));
    o1 = 1.f / (1.f + __expf(-o1));
    o2 = 1.f / (1.f + __expf(-o2));
    o3 = 1.f / (1.f + __expf(-o3));
    uint2 st;
    st.x = (unsigned)f2bf_bits(o0) | ((unsigned)f2bf_bits(o1) << 16);
    st.y = (unsigned)f2bf_bits(o2) | ((unsigned)f2bf_bits(o3) << 16);
    *(uint2*)(H + (size_t)node * 256 + lane * 4) = st;
}

// fp8 C=128 (layer-1 xs aggregation): 128B rows, uint2/16-lane, batch-8 ping-pong.
__global__ __launch_bounds__(256) void aggregate_xs8b(
    const unsigned char* __restrict__ X8,
    const int* __restrict__ colptr,
    const int* __restrict__ esrc,
    const float* __restrict__ dinv,
    unsigned short* __restrict__ xa,
    int M, int Etot)
{
    const int lane = threadIdx.x & 63;
    const int wave = threadIdx.x >> 6;
    const int l4 = lane & 15;
    const int g4 = lane >> 4;
    int node = blockIdx.x * 4 + wave;
    if (node >= M) return;

    int s = colptr[node];
    int e = colptr[node + 1];
    if (s < 0) s = 0;
    if (e > Etot) e = Etot;
    if (e < s) e = s;
    int n = e - s;

    const char* Yb = (const char*)X8;
    const unsigned lb = (unsigned)(l4 * 8);

    uint2 su = {0u, 0u};
    if (g4 == 0) su = *(const uint2*)(Yb + ((unsigned)node) * 128u + lb);

    f32x2_t a0 = {0.f, 0.f}, a1 = {0.f, 0.f}, a2 = {0.f, 0.f}, a3 = {0.f, 0.f};

    auto gat = [&](uint2* u, int base) {
        u[0] = *(const uint2*)(Yb + ((unsigned)esrc[s + base + g4]) * 128u + lb);
        u[1] = *(const uint2*)(Yb + ((unsigned)esrc[s + base + 4 + g4]) * 128u + lb);
    };
    auto acc = [&](const uint2* u) {
        #pragma unroll
        for (int k = 0; k < 2; ++k) {
            a0 += __builtin_amdgcn_cvt_pk_f32_fp8(u[k].x, false);
            a1 += __builtin_amdgcn_cvt_pk_f32_fp8(u[k].x, true);
            a2 += __builtin_amdgcn_cvt_pk_f32_fp8(u[k].y, false);
            a3 += __builtin_amdgcn_cvt_pk_f32_fp8(u[k].y, true);
        }
    };

    uint2 ua[2], ub[2];
    int NB = n >> 3;
    if (NB > 0) {
        gat(ua, 0);
        int i = 1;
        for (; i + 1 < NB; i += 2) {
            gat(ub, i << 3); acc(ua);
            gat(ua, (i + 1) << 3); acc(ub);
        }
        if (i < NB) { gat(ub, i << 3); acc(ua); acc(ub); }
        else acc(ua);
    }
    for (int t = NB << 3; t < n; t += 4) {
        if (t + g4 < n) {
            uint2 u = *(const uint2*)(Yb + ((unsigned)esrc[s + t + g4]) * 128u + lb);
            a0 += __builtin_amdgcn_cvt_pk_f32_fp8(u.x, false);
            a1 += __builtin_amdgcn_cvt_pk_f32_fp8(u.x, true);
            a2 += __builtin_amdgcn_cvt_pk_f32_fp8(u.y, false);
            a3 += __builtin_amdgcn_cvt_pk_f32_fp8(u.y, true);
        }
    }
    if (g4 == 0) {
        a0 += __builtin_amdgcn_cvt_pk_f32_fp8(su.x, false);
        a1 += __builtin_amdgcn_cvt_pk_f32_fp8(su.x, true);
        a2 += __builtin_amdgcn_cvt_pk_f32_fp8(su.y, false);
        a3 += __builtin_amdgcn_cvt_pk_f32_fp8(su.y, true);
    }

    #pragma unroll
    for (int off = 16; off < 64; off <<= 1) {
        a0[0] += __shfl_xor(a0[0], off); a0[1] += __shfl_xor(a0[1], off);
        a1[0] += __shfl_xor(a1[0], off); a1[1] += __shfl_xor(a1[1], off);
        a2[0] += __shfl_xor(a2[0], off); a2[1] += __shfl_xor(a2[1], off);
        a3[0] += __shfl_xor(a3[0], off); a3[1] += __shfl_xor(a3[1], off);
    }

    if (g4 == 0) {   // channels [l4*8, +8)
        float dv = dinv[node];
        uint4 st;
        st.x = (unsigned)f2bf_bits(a0[0] * dv) | ((unsigned)f2bf_bits(a0[1] * dv) << 16);
        st.y = (unsigned)f2bf_bits(a1[0] * dv) | ((unsigned)f2bf_bits(a1[1] * dv) << 16);
        st.z = (unsigned)f2bf_bits(a2[0] * dv) | ((unsigned)f2bf_bits(a2[1] * dv) << 16);
        st.w = (unsigned)f2bf_bits(a3[0] * dv) | ((unsigned)f2bf_bits(a3[1] * dv) << 16);
        *(uint4*)(xa + (size_t)node * 128 + l4 * 8) = st;
    }
}

// bf16 C=64, f32 out + bias (layer 3): 128B rows, uint2/16-lane, batch-8 ping-pong.
__global__ __launch_bounds__(256) void aggregate_bf16_64_v5(
    const unsigned short* __restrict__ Yin,
    const int* __restrict__ colptr,
    const int* __restrict__ esrc,
    const float* __restrict__ dinv,
    const float* __restrict__ bias,
    float* __restrict__ out,
    int M, int Etot)
{
    const int lane = threadIdx.x & 63;
    const int wave = threadIdx.x >> 6;
    const int l4 = lane & 15;
    const int g4 = lane >> 4;
    int node = blockIdx.x * 4 + wave;
    if (node >= M) return;

    int s = colptr[node];
    int e = colptr[node + 1];
    if (s < 0) s = 0;
    if (e > Etot) e = Etot;
    if (e < s) e = s;
    int n = e - s;

    const char* Yb = (const char*)Yin;
    const unsigned lb = (unsigned)(l4 * 8);

    uint2 su = {0u, 0u};
    if (g4 == 0) su = *(const uint2*)(Yb + ((unsigned)node) * 128u + lb);

    f32x2_t a0 = {0.f, 0.f}, a1 = {0.f, 0.f};

    auto gat = [&](uint2* u, int base) {
        u[0] = *(const uint2*)(Yb + ((unsigned)esrc[s + base + g4]) * 128u + lb);
        u[1] = *(const uint2*)(Yb + ((unsigned)esrc[s + base + 4 + g4]) * 128u + lb);
    };
    auto acc = [&](const uint2* u) {
        #pragma unroll
        for (int k = 0; k < 2; ++k) {
            a0 += unpack_bf2(u[k].x);
            a1 += unpack_bf2(u[k].y);
        }
    };

    uint2 ua[2], ub[2];
    int NB = n >> 3;
    if (NB > 0) {
        gat(ua, 0);
        int i = 1;
        for (; i + 1 < NB; i += 2) {
            gat(ub, i << 3); acc(ua);
            gat(ua, (i + 1) << 3); acc(ub);
        }
        if (i < NB) { gat(ub, i << 3); acc(ua); acc(ub); }
        else acc(ua);
    }
    for (int t = NB << 3; t < n; t += 4) {
        if (t + g4 < n) {
            uint2 u = *(const uint2*)(Yb + ((unsigned)esrc[s + t + g4]) * 128u + lb);
            a0 += unpack_bf2(u.x);
            a1 += unpack_bf2(u.y);
        }
    }
    if (g4 == 0) {
        a0 += unpack_bf2(su.x);
        a1 += unpack_bf2(su.y);
    }

    #pragma unroll
    for (int off = 16; off < 64; off <<= 1) {
        a0[0] += __shfl_xor(a0[0], off); a0[1] += __shfl_xor(a0[1], off);
        a1[0] += __shfl_xor(a1[0], off); a1[1] += __shfl_xor(a1[1], off);
    }

    if (g4 == 0) {   // channels [l4*4, +4)
        float dv = dinv[node];
        float4 bv = *(const float4*)(bias + l4 * 4);
        float4 st;
        st.x = a0[0] * dv + bv.x;
        st.y = a0[1] * dv + bv.y;
        st.z = a1[0] * dv + bv.z;
        st.w = a1[1] * dv + bv.w;
        *(float4*)(out + (size_t)node * 64 + l4 * 4) = st;
    }
}

// ---------------- launch ----------------

extern "C" void kernel_launch(void* const* d_in, const int* in_sizes, int n_in,
                              void* d_out, int out_size, void* d_ws, size_t ws_size,
                              hipStream_t stream)
{
    int iEI = 2, iW1 = 3, iB1 = 4, iW2 = 5, iB2 = 6, iW3 = 7, iB3 = 8;
    if (n_in == 8) { iEI = 1; iW1 = 2; iB1 = 3; iW2 = 4; iB2 = 5; iW3 = 6; iB3 = 7; }

    const float* x  = (const float*)d_in[0];
    const int* ei   = (const int*)d_in[iEI];
    const float* W1 = (const float*)d_in[iW1];
    const float* b1 = (const float*)d_in[iB1];
    const float* W2 = (const float*)d_in[iW2];
    const float* b2 = (const float*)d_in[iB2];
    const float* W3 = (const float*)d_in[iW3];
    const float* b3 = (const float*)d_in[iB3];

    const int M = in_sizes[0] / 128;     // 50000
    const int E = in_sizes[iEI] / 2;     // 800000
    const int NB = (M + 255) / 256;      // scan blocks

    auto rnd = [](size_t b) { return (b + 255) & ~(size_t)255; };
    size_t needed = rnd((size_t)M * 4)                   // dinv
                  + rnd((size_t)M * 32) * 2              // cnt8, base8 (8 XCD slices)
                  + rnd((size_t)M * 4)                   // tot
                  + rnd((size_t)(M + 1) * 4)             // colptr
                  + rnd((size_t)M * 4)                   // excl
                  + rnd((size_t)(NB + 1) * 4)            // bsum
                  + rnd((size_t)E * 4) * 4               // esrc, rank, c32, r32
                  + rnd((size_t)E)                       // xcd8
                  + rnd((size_t)256 * 128 * 2)           // Wt1
                  + rnd((size_t)256 * 256 * 2)           // Wt2
                  + rnd((size_t)64 * 256 * 2)            // Wt3
                  + rnd((size_t)M * 256 * 2) * 2;        // ybuf, hbuf
    if (ws_size < needed) {
        sentinel_fill<<<(out_size + 255) / 256, 256, 0, stream>>>((float*)d_out, out_size);
        return;
    }

    char* p = (char*)d_ws;
    auto alloc = [&](size_t bytes) {
        char* r = p;
        p += (bytes + 255) & ~(size_t)255;
        return r;
    };
    float* dinv = (float*)alloc((size_t)M * 4);
    unsigned* cnt8  = (unsigned*)alloc((size_t)M * 32);
    unsigned* base8 = (unsigned*)alloc((size_t)M * 32);
    int* tot    = (int*)alloc((size_t)M * 4);
    int* colptr = (int*)alloc((size_t)(M + 1) * 4);
    int* excl   = (int*)alloc((size_t)M * 4);
    int* bsum   = (int*)alloc((size_t)(NB + 1) * 4);
    int* esrc   = (int*)alloc((size_t)E * 4);
    int* rank   = (int*)alloc((size_t)E * 4);
    int* c32    = (int*)alloc((size_t)E * 4);
    int* r32    = (int*)alloc((size_t)E * 4);
    unsigned char* xcd8 = (unsigned char*)alloc((size_t)E);
    unsigned short* Wt1 = (unsigned short*)alloc((size_t)256 * 128 * 2);
    unsigned short* Wt2 = (unsigned short*)alloc((size_t)256 * 256 * 2);
    unsigned short* Wt3 = (unsigned short*)alloc((size_t)64 * 256 * 2);
    __hip_bfloat16* ybuf = (__hip_bfloat16*)alloc((size_t)M * 256 * 2);
    __hip_bfloat16* hbuf = (__hip_bfloat16*)alloc((size_t)M * 256 * 2);

    // region reuse inside ybuf:
    unsigned char* xs8 = (unsigned char*)ybuf;                     // M x 128 fp8 (6.4MB)
    unsigned short* xa = (unsigned short*)ybuf + (size_t)M * 128;  // M x 128 bf16 (at +12.8MB)
    unsigned char*  y8 = (unsigned char*)ybuf;                     // M x 256 fp8 row-major (after xs8 dead)

    int Mln = M * 8;
    init_zero<<<(Mln + 255) / 256, 256, 0, stream>>>(cnt8, Mln);

    count_rank_xcd<<<(E + 255) / 256, 256, 0, stream>>>(
        ei, cnt8, rank, c32, r32, xcd8, E, M);
    scan_blocks_x<<<NB, 256, 0, stream>>>(cnt8, base8, tot, excl, bsum, M);
    scan_add_dinv2<<<NB, 256, 0, stream>>>(excl, bsum, tot, colptr, dinv, M, NB);

    int gmb = (M + 127) / 128;           // 391
    int ga  = (M + 3) / 4;               // 12500
    int nfe = (E + 255) / 256;           // fill blocks (single pass)
    int nps = (M * 32 + 255) / 256;      // prescale blocks (4 ch/thread)

    // fused: single-pass CSR fill + fp8 prescale of x + weight transposes
    fill_prep_fused<<<nfe + nps + 448, 256, 0, stream>>>(
        c32, r32, xcd8, base8, colptr, rank, esrc, E,
        x, dinv, xs8, W1, W2, W3, Wt1, Wt2, Wt3, M, nfe, nps);

    // Layer 1: aggregate fp8 xs (S·x), then GEMM with fused bias+sigmoid
    aggregate_xs8b<<<ga, 256, 0, stream>>>(
        xs8, colptr, esrc, dinv, xa, M, E);
    gemm_tile<128, 128, 256, 1><<<dim3(gmb, 2), 256, 0, stream>>>(
        (const __bf16*)xa, Wt1, dinv, b1, hbuf, M);
    // Layer 2: GEMM -> fp8 table (row-major), fp8 gather aggregate -> bf16 h2
    gemm_tile<256, 128, 256, 2><<<dim3(gmb, 2), 256, 0, stream>>>(
        (const __bf16*)hbuf, Wt2, dinv, b2, y8, M);
    aggregate_fp8_v4<<<ga, 256, 0, stream>>>(
        y8, colptr, esrc, dinv, b2, (unsigned short*)hbuf, M, E);
    // Layer 3: bf16
    gemm_tile<256, 64, 64, 0><<<dim3(gmb, 1), 256, 0, stream>>>(
        (const __bf16*)hbuf, Wt3, dinv, b3, ybuf, M);
    aggregate_bf16_64_v5<<<ga, 256, 0, stream>>>(
        (const unsigned short*)ybuf, colptr, esrc, dinv, b3, (float*)d_out, M, E);
}